// Round 3
// baseline (157.818 us; speedup 1.0000x reference)
//
#include <hip/hip_runtime.h>
#include <hip/hip_bf16.h>

#define NSPLIT 16
#define BIGF 1e30f
#define MARGIN 0.3f
#define DK 128
#define LDA 136   // padded LDS stride (bf16 elems)

typedef __attribute__((ext_vector_type(8))) short bf16x8;
typedef __attribute__((ext_vector_type(4))) float f32x4;

// workspace word offsets
#define WS_HIST 0                  // 1024 u32 label histogram
#define WS_HP   1024               // 8192 u32: max d2_pos bits (init 0)
#define WS_HN   (1024 + 8192)      // 8192 u32: max ~d2_neg bits (init 0 => min via complement)
#define WS_GSUM (1024 + 16384)     // f32 sum
#define WS_GCNT (WS_GSUM + 1)      // f32 cnt
#define WS_BCNT (WS_GSUM + 2)      // u32 block counter
#define WS_SQ   (WS_GSUM + 4)      // 8192 f32 squared norms (16B aligned)
#define WS_XB   (WS_SQ + 8192)     // bf16 copy of X (byte off 102416, 16B aligned)

// Kernel 1: bf16 copy of X + exact fp32 squared norms + label histogram.
__global__ void prep_kernel(const float* __restrict__ x, ushort* __restrict__ xb,
                            float* __restrict__ sq, unsigned* __restrict__ hist,
                            const int* __restrict__ lab, int N) {
    int wave = threadIdx.x >> 6;
    int lane = threadIdx.x & 63;
    int row = blockIdx.x * 4 + wave;
    if (row >= N) return;
    const float2* xr = (const float2*)(x + (size_t)row * DK);
    float2 v = xr[lane];
    __hip_bfloat16 b0 = __float2bfloat16(v.x);
    __hip_bfloat16 b1 = __float2bfloat16(v.y);
    ushort2 st;
    st.x = *(ushort*)&b0;
    st.y = *(ushort*)&b1;
    ((ushort2*)(xb + (size_t)row * DK))[lane] = st;
    float s = v.x * v.x + v.y * v.y;
    #pragma unroll
    for (int o = 32; o > 0; o >>= 1) s += __shfl_xor(s, o, 64);
    if (lane == 0) {
        sq[row] = s;
        atomicAdd(&hist[lab[row]], 1u);
    }
}

// Kernel 2: fused bf16-MFMA dist^2 tile + masked max/min in t = sqb - 2*dot domain.
// Grid (N/128, NSPLIT); 4 waves per block, each owns a 64x64 quadrant.
// Diagonal is same-label => auto-excluded from hn; included in hp (d2~0, never wins;
// validity handled exactly via histogram in finalize).
__global__ __launch_bounds__(256, 3) void tile_kernel(
    const ushort* __restrict__ xb, const float* __restrict__ sq,
    const int* __restrict__ lab,
    unsigned* __restrict__ hp_bits, unsigned* __restrict__ hn_comp, int N)
{
    __shared__ ushort a_s[128 * LDA];
    __shared__ int   laba_s[128];
    __shared__ float red_hp[128][2];
    __shared__ float red_hn[128][2];

    const int tid  = threadIdx.x;
    const int lane = tid & 63;
    const int wave = tid >> 6;
    const int m16  = lane & 15;
    const int quad = lane >> 4;
    const int rbase = blockIdx.x * 128;
    const int wrow = (wave >> 1) * 64;
    const int wcol = (wave & 1) * 64;

    for (int c = tid; c < 128 * 16; c += 256) {
        int r = c >> 4, c8 = c & 15;
        *(bf16x8*)(a_s + r * LDA + c8 * 8) =
            *(const bf16x8*)(xb + (size_t)(rbase + r) * DK + c8 * 8);
    }
    if (tid < 128) laba_s[tid] = lab[rbase + tid];
    __syncthreads();

    int rlab[4][4];
    #pragma unroll
    for (int mt = 0; mt < 4; ++mt)
        #pragma unroll
        for (int r = 0; r < 4; ++r)
            rlab[mt][r] = laba_s[wrow + mt * 16 + quad * 4 + r];

    float runhp[4][4], runhn[4][4];
    #pragma unroll
    for (int mt = 0; mt < 4; ++mt)
        #pragma unroll
        for (int r = 0; r < 4; ++r) { runhp[mt][r] = -BIGF; runhn[mt][r] = BIGF; }

    const int cols_per_split = N / NSPLIT;   // 512
    const int cbegin = blockIdx.y * cols_per_split;

    for (int ci = 0; ci < cols_per_split; ci += 128) {
        const int cbase = cbegin + ci;

        // per-lane column attrs (prefetched ahead of the k-loop MFMAs)
        float sqbv[4]; int lbv[4];
        #pragma unroll
        for (int nt = 0; nt < 4; ++nt) {
            int colg = cbase + wcol + nt * 16 + m16;
            sqbv[nt] = sq[colg];
            lbv[nt]  = lab[colg];
        }

        f32x4 acc[4][4];
        #pragma unroll
        for (int mt = 0; mt < 4; ++mt)
            #pragma unroll
            for (int nt = 0; nt < 4; ++nt)
                acc[mt][nt] = (f32x4){0.f, 0.f, 0.f, 0.f};

        #pragma unroll
        for (int s = 0; s < 4; ++s) {
            bf16x8 bfr[4], afr[4];
            #pragma unroll
            for (int nt = 0; nt < 4; ++nt)
                bfr[nt] = *(const bf16x8*)(xb + (size_t)(cbase + wcol + nt * 16 + m16) * DK
                                           + s * 32 + quad * 8);
            #pragma unroll
            for (int mt = 0; mt < 4; ++mt)
                afr[mt] = *(const bf16x8*)(a_s + (wrow + mt * 16 + m16) * LDA
                                           + s * 32 + quad * 8);
            #pragma unroll
            for (int mt = 0; mt < 4; ++mt)
                #pragma unroll
                for (int nt = 0; nt < 4; ++nt)
                    acc[mt][nt] = __builtin_amdgcn_mfma_f32_16x16x32_bf16(
                        afr[mt], bfr[nt], acc[mt][nt], 0, 0, 0);
        }

        #pragma unroll
        for (int nt = 0; nt < 4; ++nt) {
            #pragma unroll
            for (int mt = 0; mt < 4; ++mt) {
                #pragma unroll
                for (int r = 0; r < 4; ++r) {
                    float t = fmaf(-2.0f, acc[mt][nt][r], sqbv[nt]);
                    bool same = (rlab[mt][r] == lbv[nt]);
                    runhp[mt][r] = fmaxf(runhp[mt][r], same ? t : -BIGF);
                    runhn[mt][r] = fminf(runhn[mt][r], same ? BIGF : t);
                }
            }
        }
    }

    // reduce across the 16 m16-lanes sharing each row
    #pragma unroll
    for (int mt = 0; mt < 4; ++mt)
        #pragma unroll
        for (int r = 0; r < 4; ++r) {
            #pragma unroll
            for (int o = 8; o > 0; o >>= 1) {
                runhp[mt][r] = fmaxf(runhp[mt][r], __shfl_xor(runhp[mt][r], o, 16));
                runhn[mt][r] = fminf(runhn[mt][r], __shfl_xor(runhn[mt][r], o, 16));
            }
        }

    if (m16 == 0) {
        #pragma unroll
        for (int mt = 0; mt < 4; ++mt)
            #pragma unroll
            for (int r = 0; r < 4; ++r) {
                int rowl = wrow + mt * 16 + quad * 4 + r;
                red_hp[rowl][wave & 1] = runhp[mt][r];
                red_hn[rowl][wave & 1] = runhn[mt][r];
            }
    }
    __syncthreads();
    if (tid < 128) {
        float thp = fmaxf(red_hp[tid][0], red_hp[tid][1]);
        float thn = fminf(red_hn[tid][0], red_hn[tid][1]);
        float sqa = sq[rbase + tid];
        float d2p = fmaxf(sqa + thp, 0.0f);   // clamp == reference's max(d2,0)
        float d2n = fmaxf(sqa + thn, 0.0f);
        atomicMax(&hp_bits[rbase + tid], __float_as_uint(d2p));
        atomicMax(&hn_comp[rbase + tid], ~__float_as_uint(d2n));  // min via complement
    }
}

// Kernel 3: per-row loss + grid reduction; last block writes the scalar.
__global__ void finalize_kernel(const unsigned* __restrict__ hp_bits,
                                const unsigned* __restrict__ hn_comp,
                                const int* __restrict__ lab,
                                const unsigned* __restrict__ hist,
                                float* __restrict__ gsum, float* __restrict__ gcnt,
                                unsigned* __restrict__ bcount,
                                float* __restrict__ out, int N)
{
    __shared__ float s_sum[256];
    __shared__ float s_cnt[256];
    int tid = threadIdx.x;
    int row = blockIdx.x * 256 + tid;
    float loss = 0.0f, cv = 0.0f;
    if (row < N) {
        unsigned c = hist[lab[row]];
        bool valid = (c >= 2u) && (c < (unsigned)N);
        if (valid) {
            float dp = sqrtf(__uint_as_float(hp_bits[row]));
            float dn = sqrtf(__uint_as_float(~hn_comp[row]));
            loss = fmaxf(dp - dn + MARGIN, 0.0f);
            cv = 1.0f;
        }
    }
    s_sum[tid] = loss; s_cnt[tid] = cv;
    __syncthreads();
    for (int o = 128; o > 0; o >>= 1) {
        if (tid < o) { s_sum[tid] += s_sum[tid + o]; s_cnt[tid] += s_cnt[tid + o]; }
        __syncthreads();
    }
    if (tid == 0) {
        atomicAdd(gsum, s_sum[0]);
        atomicAdd(gcnt, s_cnt[0]);
        __threadfence();
        unsigned old = atomicAdd(bcount, 1u);
        if (old == gridDim.x - 1) {
            float s = atomicAdd(gsum, 0.0f);   // coherent read
            float c = atomicAdd(gcnt, 0.0f);
            out[0] = (c > 0.0f) ? s / c : 0.0f;
        }
    }
}

extern "C" void kernel_launch(void* const* d_in, const int* in_sizes, int n_in,
                              void* d_out, int out_size, void* d_ws, size_t ws_size,
                              hipStream_t stream) {
    const float* x = (const float*)d_in[0];
    const int* lab = (const int*)d_in[1];
    float* out = (float*)d_out;
    const int N = in_sizes[1];          // 8192

    unsigned* ws = (unsigned*)d_ws;
    unsigned* hist    = ws + WS_HIST;
    unsigned* hp_bits = ws + WS_HP;
    unsigned* hn_comp = ws + WS_HN;
    float* gsum = (float*)(ws + WS_GSUM);
    float* gcnt = (float*)(ws + WS_GCNT);
    unsigned* bcount = ws + WS_BCNT;
    float* sq = (float*)(ws + WS_SQ);
    ushort* xb = (ushort*)(ws + WS_XB);

    hipMemsetAsync(d_ws, 0, (size_t)WS_SQ * sizeof(unsigned), stream);
    prep_kernel<<<N / 4, 256, 0, stream>>>(x, xb, sq, hist, lab, N);
    dim3 grid(N / 128, NSPLIT);
    tile_kernel<<<grid, 256, 0, stream>>>(xb, sq, lab, hp_bits, hn_comp, N);
    finalize_kernel<<<N / 256, 256, 0, stream>>>(hp_bits, hn_comp, lab, hist,
                                                 gsum, gcnt, bcount, out, N);
}

// Round 4
// 113.988 us; speedup vs baseline: 1.3845x; 1.3845x over previous
//
#include <hip/hip_runtime.h>
#include <hip/hip_bf16.h>

#define NSPLIT 16
#define BIGF 1e30f
#define MARGIN 0.3f
#define DK 128
#define LDA 136   // padded LDS stride (bf16 elems)

typedef __attribute__((ext_vector_type(8))) short bf16x8;
typedef __attribute__((ext_vector_type(4))) float f32x4;

// workspace word offsets
#define WS_HIST 0                  // 1024 u32 label histogram
#define WS_HP   1024               // 8192 u32: max d2_pos bits (init 0)
#define WS_HN   (1024 + 8192)      // 8192 u32: max ~d2_neg bits (init 0 => min via complement)
#define WS_GSUM (1024 + 16384)     // f32 sum
#define WS_GCNT (WS_GSUM + 1)      // f32 cnt
#define WS_BCNT (WS_GSUM + 2)      // u32 block counter
#define WS_SQ   (WS_GSUM + 4)      // 8192 f32 squared norms (16B aligned)
#define WS_XB   (WS_SQ + 8192)     // bf16 copy of X (16B aligned)

// Kernel 1: bf16 copy of X + exact fp32 squared norms + label histogram.
__global__ void prep_kernel(const float* __restrict__ x, ushort* __restrict__ xb,
                            float* __restrict__ sq, unsigned* __restrict__ hist,
                            const int* __restrict__ lab, int N) {
    int wave = threadIdx.x >> 6;
    int lane = threadIdx.x & 63;
    int row = blockIdx.x * 4 + wave;
    if (row >= N) return;
    const float2* xr = (const float2*)(x + (size_t)row * DK);
    float2 v = xr[lane];
    __hip_bfloat16 b0 = __float2bfloat16(v.x);
    __hip_bfloat16 b1 = __float2bfloat16(v.y);
    ushort2 st;
    st.x = *(ushort*)&b0;
    st.y = *(ushort*)&b1;
    ((ushort2*)(xb + (size_t)row * DK))[lane] = st;
    float s = v.x * v.x + v.y * v.y;
    #pragma unroll
    for (int o = 32; o > 0; o >>= 1) s += __shfl_xor(s, o, 64);
    if (lane == 0) {
        sq[row] = s;
        atomicAdd(&hist[lab[row]], 1u);
    }
}

// Kernel 2: fused bf16-MFMA dist^2 tile + masked max/min in t = sqb - 2*dot domain.
// Grid (N/128, NSPLIT); 4 waves per block, each owns a 64x64 quadrant.
// launch_bounds min-waves kept at 2: a higher value re-caps the unified RF and
// spills the accumulators to scratch (round-3 regression: 79 MB WRITE_SIZE).
// Occupancy comes from the grid: 1024 blocks, ~128 VGPR, 37.9 KB LDS -> 4 blocks/CU.
__global__ __launch_bounds__(256, 2) void tile_kernel(
    const ushort* __restrict__ xb, const float* __restrict__ sq,
    const int* __restrict__ lab,
    unsigned* __restrict__ hp_bits, unsigned* __restrict__ hn_comp, int N)
{
    __shared__ ushort a_s[128 * LDA];
    __shared__ int   laba_s[128];
    __shared__ float red_hp[128][2];
    __shared__ float red_hn[128][2];

    const int tid  = threadIdx.x;
    const int lane = tid & 63;
    const int wave = tid >> 6;
    const int m16  = lane & 15;
    const int quad = lane >> 4;
    const int rbase = blockIdx.x * 128;
    const int wrow = (wave >> 1) * 64;
    const int wcol = (wave & 1) * 64;

    for (int c = tid; c < 128 * 16; c += 256) {
        int r = c >> 4, c8 = c & 15;
        *(bf16x8*)(a_s + r * LDA + c8 * 8) =
            *(const bf16x8*)(xb + (size_t)(rbase + r) * DK + c8 * 8);
    }
    if (tid < 128) laba_s[tid] = lab[rbase + tid];
    __syncthreads();

    int rlab[4][4];
    #pragma unroll
    for (int mt = 0; mt < 4; ++mt)
        #pragma unroll
        for (int r = 0; r < 4; ++r)
            rlab[mt][r] = laba_s[wrow + mt * 16 + quad * 4 + r];

    float runhp[4][4], runhn[4][4];
    #pragma unroll
    for (int mt = 0; mt < 4; ++mt)
        #pragma unroll
        for (int r = 0; r < 4; ++r) { runhp[mt][r] = -BIGF; runhn[mt][r] = BIGF; }

    const int cols_per_split = N / NSPLIT;   // 512
    const int cbegin = blockIdx.y * cols_per_split;

    for (int ci = 0; ci < cols_per_split; ci += 128) {
        const int cbase = cbegin + ci;

        float sqbv[4]; int lbv[4];
        #pragma unroll
        for (int nt = 0; nt < 4; ++nt) {
            int colg = cbase + wcol + nt * 16 + m16;
            sqbv[nt] = sq[colg];
            lbv[nt]  = lab[colg];
        }

        f32x4 acc[4][4];
        #pragma unroll
        for (int mt = 0; mt < 4; ++mt)
            #pragma unroll
            for (int nt = 0; nt < 4; ++nt)
                acc[mt][nt] = (f32x4){0.f, 0.f, 0.f, 0.f};

        #pragma unroll
        for (int s = 0; s < 4; ++s) {
            bf16x8 bfr[4], afr[4];
            #pragma unroll
            for (int nt = 0; nt < 4; ++nt)
                bfr[nt] = *(const bf16x8*)(xb + (size_t)(cbase + wcol + nt * 16 + m16) * DK
                                           + s * 32 + quad * 8);
            #pragma unroll
            for (int mt = 0; mt < 4; ++mt)
                afr[mt] = *(const bf16x8*)(a_s + (wrow + mt * 16 + m16) * LDA
                                           + s * 32 + quad * 8);
            #pragma unroll
            for (int mt = 0; mt < 4; ++mt)
                #pragma unroll
                for (int nt = 0; nt < 4; ++nt)
                    acc[mt][nt] = __builtin_amdgcn_mfma_f32_16x16x32_bf16(
                        afr[mt], bfr[nt], acc[mt][nt], 0, 0, 0);
        }

        #pragma unroll
        for (int nt = 0; nt < 4; ++nt) {
            #pragma unroll
            for (int mt = 0; mt < 4; ++mt) {
                #pragma unroll
                for (int r = 0; r < 4; ++r) {
                    float t = fmaf(-2.0f, acc[mt][nt][r], sqbv[nt]);
                    bool same = (rlab[mt][r] == lbv[nt]);
                    runhp[mt][r] = fmaxf(runhp[mt][r], same ? t : -BIGF);
                    runhn[mt][r] = fminf(runhn[mt][r], same ? BIGF : t);
                }
            }
        }
    }

    // reduce across the 16 m16-lanes sharing each row
    #pragma unroll
    for (int mt = 0; mt < 4; ++mt)
        #pragma unroll
        for (int r = 0; r < 4; ++r) {
            #pragma unroll
            for (int o = 8; o > 0; o >>= 1) {
                runhp[mt][r] = fmaxf(runhp[mt][r], __shfl_xor(runhp[mt][r], o, 16));
                runhn[mt][r] = fminf(runhn[mt][r], __shfl_xor(runhn[mt][r], o, 16));
            }
        }

    if (m16 == 0) {
        #pragma unroll
        for (int mt = 0; mt < 4; ++mt)
            #pragma unroll
            for (int r = 0; r < 4; ++r) {
                int rowl = wrow + mt * 16 + quad * 4 + r;
                red_hp[rowl][wave & 1] = runhp[mt][r];
                red_hn[rowl][wave & 1] = runhn[mt][r];
            }
    }
    __syncthreads();
    if (tid < 128) {
        float thp = fmaxf(red_hp[tid][0], red_hp[tid][1]);
        float thn = fminf(red_hn[tid][0], red_hn[tid][1]);
        float sqa = sq[rbase + tid];
        float d2p = fmaxf(sqa + thp, 0.0f);   // clamp == reference's max(d2,0)
        float d2n = fmaxf(sqa + thn, 0.0f);
        atomicMax(&hp_bits[rbase + tid], __float_as_uint(d2p));
        atomicMax(&hn_comp[rbase + tid], ~__float_as_uint(d2n));  // min via complement
    }
}

// Kernel 3: per-row loss + grid reduction; last block writes the scalar.
__global__ void finalize_kernel(const unsigned* __restrict__ hp_bits,
                                const unsigned* __restrict__ hn_comp,
                                const int* __restrict__ lab,
                                const unsigned* __restrict__ hist,
                                float* __restrict__ gsum, float* __restrict__ gcnt,
                                unsigned* __restrict__ bcount,
                                float* __restrict__ out, int N)
{
    __shared__ float s_sum[256];
    __shared__ float s_cnt[256];
    int tid = threadIdx.x;
    int row = blockIdx.x * 256 + tid;
    float loss = 0.0f, cv = 0.0f;
    if (row < N) {
        unsigned c = hist[lab[row]];
        bool valid = (c >= 2u) && (c < (unsigned)N);
        if (valid) {
            float dp = sqrtf(__uint_as_float(hp_bits[row]));
            float dn = sqrtf(__uint_as_float(~hn_comp[row]));
            loss = fmaxf(dp - dn + MARGIN, 0.0f);
            cv = 1.0f;
        }
    }
    s_sum[tid] = loss; s_cnt[tid] = cv;
    __syncthreads();
    for (int o = 128; o > 0; o >>= 1) {
        if (tid < o) { s_sum[tid] += s_sum[tid + o]; s_cnt[tid] += s_cnt[tid + o]; }
        __syncthreads();
    }
    if (tid == 0) {
        atomicAdd(gsum, s_sum[0]);
        atomicAdd(gcnt, s_cnt[0]);
        __threadfence();
        unsigned old = atomicAdd(bcount, 1u);
        if (old == gridDim.x - 1) {
            float s = atomicAdd(gsum, 0.0f);   // coherent read
            float c = atomicAdd(gcnt, 0.0f);
            out[0] = (c > 0.0f) ? s / c : 0.0f;
        }
    }
}

extern "C" void kernel_launch(void* const* d_in, const int* in_sizes, int n_in,
                              void* d_out, int out_size, void* d_ws, size_t ws_size,
                              hipStream_t stream) {
    const float* x = (const float*)d_in[0];
    const int* lab = (const int*)d_in[1];
    float* out = (float*)d_out;
    const int N = in_sizes[1];          // 8192

    unsigned* ws = (unsigned*)d_ws;
    unsigned* hist    = ws + WS_HIST;
    unsigned* hp_bits = ws + WS_HP;
    unsigned* hn_comp = ws + WS_HN;
    float* gsum = (float*)(ws + WS_GSUM);
    float* gcnt = (float*)(ws + WS_GCNT);
    unsigned* bcount = ws + WS_BCNT;
    float* sq = (float*)(ws + WS_SQ);
    ushort* xb = (ushort*)(ws + WS_XB);

    hipMemsetAsync(d_ws, 0, (size_t)WS_SQ * sizeof(unsigned), stream);
    prep_kernel<<<N / 4, 256, 0, stream>>>(x, xb, sq, hist, lab, N);
    dim3 grid(N / 128, NSPLIT);
    tile_kernel<<<grid, 256, 0, stream>>>(xb, sq, lab, hp_bits, hn_comp, N);
    finalize_kernel<<<N / 256, 256, 0, stream>>>(hp_bits, hn_comp, lab, hist,
                                                 gsum, gcnt, bcount, out, N);
}